// Round 20
// baseline (279.601 us; speedup 1.0000x reference)
//
#include <hip/hip_runtime.h>
#include <math.h>

// Fused TowersMLP, bf16-MFMA, transposed-D, 256-thread / 4-wave.
// R20 = R19 (green 209us: in-place tw2, single-arena overlays, 4 blocks/CU)
// + CH RESIDUAL IN BF16: live set 39168 -> 32640 B -> 5 blocks/CU (20 waves).
// CH touched at 3 points (tw3 write, attn-proj rmw, ff2/LN reads) - each
// bf16-rounds ~0.4% rel; LN renormalizes, predicted absmax ~2e-4 < 2.93e-4.
// Frozen invariants: split lgkm barrier (R7 form), bias in epilogue only
// (bias-fold POISON), 8192-block dispatch (persistent grid POISON).

typedef short s8v __attribute__((ext_vector_type(8)));
typedef float f4v __attribute__((ext_vector_type(4)));
typedef int   i2v __attribute__((ext_vector_type(2)));
typedef int   i4v __attribute__((ext_vector_type(4)));

__device__ __forceinline__ short f2bf(float f) {
    unsigned u = __float_as_uint(f);
    unsigned r = (u + 0x7fffu + ((u >> 16) & 1u)) >> 16;   // RNE
    return (short)r;
}
__device__ __forceinline__ int cvt_pk_bf16(float a, float b) {   // lo=a, hi=b
    int r;
    asm("v_cvt_pk_bf16_f32 %0, %1, %2" : "=v"(r) : "v"(a), "v"(b));
    return r;
}
__device__ __forceinline__ float bf_lo(int w) { return __uint_as_float((unsigned)w << 16); }
__device__ __forceinline__ float bf_hi(int w) { return __uint_as_float((unsigned)w & 0xffff0000u); }
__device__ __forceinline__ float silu_f(float v) {
    return v * __builtin_amdgcn_rcpf(1.0f + __expf(-v));   // rcp, arg >= 1
}

// lgkm-only barrier (R7 split form — PROVEN; do not combine into one asm).
#define BARRIER() do {                                        \
    asm volatile("s_waitcnt lgkmcnt(0)" ::: "memory");        \
    __builtin_amdgcn_s_barrier();                             \
    __builtin_amdgcn_sched_barrier(0);                        \
} while (0)

// ---- packed weight offsets (bf16 elems), layout [nt][ks][lane(64)][8] ----
#define OFF_T1F  0        // 256 x 32 fused tw1@BD   NT=16 KS=1
#define OFF_TW2  8192     // 256 x 256  NT=16 KS=8
#define OFF_TW3  73728    // 64 x 256   NT=4  KS=8
#define OFF_INP  90112    // 192 x 64   NT=12 KS=2
#define OFF_OUT  102400   // 64 x 64    NT=4  KS=2
#define OFF_FF1  106496   // 128 x 64   NT=8  KS=2
#define OFF_FF2  114688   // 64 x 128   NT=4  KS=4
#define OFF_HW1  122880   // 160 x 192  NT=10 KS=6
#define OFF_HW2  153600   // 64 x 160   NT=4  KS=5
#define BIAS1_ELEM 163840 // f32[3][256] pos-dependent tower bias (3072 B)
// total ws: 163840*2 + 3072 = 330752 B

__global__ void pack_weights(const float* __restrict__ w_emb, const float* __restrict__ tw1,
                             const float* __restrict__ pos_d, const float* __restrict__ tb1,
                             const float* __restrict__ tw2, const float* __restrict__ tw3,
                             const float* __restrict__ inpw, const float* __restrict__ outw,
                             const float* __restrict__ ffw1, const float* __restrict__ ffw2,
                             const float* __restrict__ hw1, const float* __restrict__ hw2,
                             short* __restrict__ dst)
{
    int L = blockIdx.y;
    if (L == 0) {
        int total = 16 * 512;
        for (int e = blockIdx.x * blockDim.x + threadIdx.x; e < total; e += gridDim.x * blockDim.x) {
            int nt = e >> 9, q = e & 511;
            int l = q >> 3, j = q & 7;
            int n = nt * 16 + (l & 15);
            int k = (l >> 4) * 8 + j;
            float v = 0.f;
            if (k < 30) {
                int gl = k / 10, kk = k - gl * 10;
                const float* trow = tw1 + n * 72 + gl * 24;
                for (int jj = 0; jj < 24; ++jj) v += trow[jj] * w_emb[jj * 10 + kk];
            }
            dst[OFF_T1F + e] = f2bf(v);
        }
        return;
    }
    if (L == 9) {
        float* b1 = (float*)(dst + BIAS1_ELEM);
        for (int e = blockIdx.x * blockDim.x + threadIdx.x; e < 768; e += gridDim.x * blockDim.x) {
            int pos = e >> 8, n = e & 255;
            float v = tb1[n];
            for (int j = 0; j < 72; ++j)
                v += tw1[n * 72 + j] * pos_d[(pos * 3 + j / 24) * 24 + (j % 24)];
            b1[e] = v;
        }
        return;
    }
    const float* W; int K, KS, N, off;
    switch (L) {
      case 1: W = tw2;  K = 256; KS = 8; N = 256; off = OFF_TW2; break;
      case 2: W = tw3;  K = 256; KS = 8; N = 64;  off = OFF_TW3; break;
      case 3: W = inpw; K = 64;  KS = 2; N = 192; off = OFF_INP; break;
      case 4: W = outw; K = 64;  KS = 2; N = 64;  off = OFF_OUT; break;
      case 5: W = ffw1; K = 64;  KS = 2; N = 128; off = OFF_FF1; break;
      case 6: W = ffw2; K = 128; KS = 4; N = 64;  off = OFF_FF2; break;
      case 7: W = hw1;  K = 192; KS = 6; N = 160; off = OFF_HW1; break;
      default:W = hw2;  K = 160; KS = 5; N = 64;  off = OFF_HW2; break;
    }
    int total = (N >> 4) * KS * 512;
    for (int e = blockIdx.x * blockDim.x + threadIdx.x; e < total; e += gridDim.x * blockDim.x) {
        int nt = e / (KS * 512);
        int r  = e - nt * (KS * 512);
        int ks = r >> 9;
        int q  = r & 511;
        int l  = q >> 3, j = q & 7;
        int n  = nt * 16 + (l & 15);
        int k  = ks * 32 + (l >> 4) * 8 + j;
        dst[off + e] = f2bf((k < K) ? W[n * K + k] : 0.0f);
    }
}

// ---- weight preload (first-tile fragments held across barriers) ----
template<int KSH> struct PreW { s8v w[KSH]; };

template<int KSH>
__device__ __forceinline__ PreW<KSH> preloadW(const short* __restrict__ Wp,
                                              int lane, int nt, int ksTotal) {
    PreW<KSH> p;
    #pragma unroll
    for (int ks = 0; ks < KSH; ++ks)
        p.w[ks] = *(const s8v*)(Wp + nt * (ksTotal * 512) + ks * 512 + lane * 8);
    return p;
}

// ---- shared epilogue (bias added HERE — never in MFMA C); OP compile-time ----
// CH is bf16 [48][68] now. EPI:
//  0 silu->bf16, 1 linear->bf16,
//  2 CHb rmw: CHb[t][n0..3] += acc+bias (bf16 in/out)
//  3 CHb write: cvt(acc+bias+pos_c)
//  5 residual: CHb + acc + bias -> flat bf16 [16][OP] (aux = CHb via cast)
//  6 silu(acc+bias) dot hw3 -> f32 partial [16][16]
//  7 silu(acc + B1[t%3]) -> bf16 (bv unused)
template<int EPI, int OP>
__device__ __forceinline__ void epi_store(f4v acc, f4v bv, int t, int n0, void* Out,
                                          const void* aux)
{
    if (EPI == 0 || EPI == 1) {
        float v0 = acc[0] + bv[0], v1 = acc[1] + bv[1];
        float v2 = acc[2] + bv[2], v3 = acc[3] + bv[3];
        if (EPI == 0) { v0 = silu_f(v0); v1 = silu_f(v1); v2 = silu_f(v2); v3 = silu_f(v3); }
        i2v pk; pk[0] = cvt_pk_bf16(v0, v1); pk[1] = cvt_pk_bf16(v2, v3);
        *(i2v*)((short*)Out + t * OP + n0) = pk;
    } else if (EPI == 2) {
        i2v* p = (i2v*)((short*)Out + t * 68 + n0);
        i2v c = *p;
        float o0 = bf_lo(c[0]) + acc[0] + bv[0];
        float o1 = bf_hi(c[0]) + acc[1] + bv[1];
        float o2 = bf_lo(c[1]) + acc[2] + bv[2];
        float o3 = bf_hi(c[1]) + acc[3] + bv[3];
        i2v pk; pk[0] = cvt_pk_bf16(o0, o1); pk[1] = cvt_pk_bf16(o2, o3);
        *p = pk;
    } else if (EPI == 3) {
        const float* pc = (const float*)aux + (t % 3) * 64 + n0;
        i2v pk;
        pk[0] = cvt_pk_bf16(acc[0] + bv[0] + pc[0], acc[1] + bv[1] + pc[1]);
        pk[1] = cvt_pk_bf16(acc[2] + bv[2] + pc[2], acc[3] + bv[3] + pc[3]);
        *(i2v*)((short*)Out + t * 68 + n0) = pk;
    } else if (EPI == 5) {
        const short* chb = (const short*)aux;
        i2v c = *(const i2v*)(chb + t * 68 + n0);
        int rr = t / 3, cc = t - rr * 3;
        i2v pk;
        pk[0] = cvt_pk_bf16(bf_lo(c[0]) + acc[0] + bv[0], bf_hi(c[0]) + acc[1] + bv[1]);
        pk[1] = cvt_pk_bf16(bf_lo(c[1]) + acc[2] + bv[2], bf_hi(c[1]) + acc[3] + bv[3]);
        *(i2v*)((short*)Out + rr * OP + cc * 64 + n0) = pk;
    } else if (EPI == 6) {
        const float* w = (const float*)aux + n0;
        float p = silu_f(acc[0] + bv[0]) * w[0] + silu_f(acc[1] + bv[1]) * w[1]
                + silu_f(acc[2] + bv[2]) * w[2] + silu_f(acc[3] + bv[3]) * w[3];
        ((float*)Out)[t * OP + (n0 >> 2)] = p;
    } else {
        const float* bp = (const float*)aux + (t % 3) * 256 + n0;
        float v0 = silu_f(acc[0] + bp[0]), v1 = silu_f(acc[1] + bp[1]);
        float v2 = silu_f(acc[2] + bp[2]), v3 = silu_f(acc[3] + bp[3]);
        i2v pk; pk[0] = cvt_pk_bf16(v0, v1); pk[1] = cvt_pk_bf16(v2, v3);
        *(i2v*)((short*)Out + t * OP + n0) = pk;
    }
}

// ---- generic transposed MFMA dense layer, preloaded first tile ----
template<int MT, int KS, int EPI, int AP, int OP>
__device__ __forceinline__ void mfma_T(
    const short* __restrict__ Wp,
    const float* __restrict__ bias,
    const short* A, void* Out, int N,
    const void* aux, int lane, int wid, PreW<KS> pre)
{
    const int l15 = lane & 15, l4 = lane >> 4;
    s8v xf[MT][KS];
    #pragma unroll
    for (int m = 0; m < MT; ++m)
        #pragma unroll
        for (int ks = 0; ks < KS; ++ks)
            xf[m][ks] = *(const s8v*)(A + (m * 16 + l15) * AP + ks * 32 + l4 * 8);

    s8v wf[KS];
    #pragma unroll
    for (int ks = 0; ks < KS; ++ks) wf[ks] = pre.w[ks];

    const int NT = N >> 4;
    for (int nt = wid; nt < NT; nt += 4) {
        s8v wfn[KS];
        const bool more = (nt + 4) < NT;
        if (more) {
            #pragma unroll
            for (int ks = 0; ks < KS; ++ks)
                wfn[ks] = *(const s8v*)(Wp + (nt + 4) * (KS * 512) + ks * 512 + lane * 8);
        }
        const int n0 = nt * 16 + l4 * 4;
        f4v bv = {0.f, 0.f, 0.f, 0.f};
        if (EPI != 7) bv = *(const f4v*)(bias + n0);
        #pragma unroll
        for (int m = 0; m < MT; ++m) {
            f4v acc = {0.f, 0.f, 0.f, 0.f};
            #pragma unroll
            for (int ks = 0; ks < KS; ++ks)
                acc = __builtin_amdgcn_mfma_f32_16x16x32_bf16(wf[ks], xf[m][ks], acc, 0, 0, 0);
            epi_store<EPI, OP>(acc, bv, m * 16 + l15, n0, Out, aux);
        }
        if (more) {
            #pragma unroll
            for (int ks = 0; ks < KS; ++ks) wf[ks] = wfn[ks];
        }
    }
}

// ---- fused first layer: A-fragments loaded DIRECTLY from global x ----
template<int OP>
__device__ __forceinline__ void mfma_x1(
    const short* __restrict__ Wp, const float* __restrict__ x, long long row0,
    void* Out, const float* __restrict__ bias1,
    int lane, int wid, PreW<1> pre)
{
    const int l15 = lane & 15, l4 = lane >> 4;
    s8v xf[3];
    #pragma unroll
    for (int m = 0; m < 3; ++m) {
        int t = m * 16 + l15;
        int r = t / 3, c = t - r * 3;
        const float* xp = x + (row0 + r) * 90 + c * 30 + l4 * 8;
        float2 a = *(const float2*)xp;
        float2 b = *(const float2*)(xp + 2);
        float2 d = *(const float2*)(xp + 4);
        float2 e = (l4 < 3) ? *(const float2*)(xp + 6) : make_float2(0.f, 0.f);
        i4v pk;
        pk[0] = cvt_pk_bf16(a.x, a.y);
        pk[1] = cvt_pk_bf16(b.x, b.y);
        pk[2] = cvt_pk_bf16(d.x, d.y);
        pk[3] = cvt_pk_bf16(e.x, e.y);
        xf[m] = *(s8v*)&pk;
    }

    s8v wf = pre.w[0];
    for (int nt = wid; nt < 16; nt += 4) {
        s8v wfn;
        const bool more = (nt + 4) < 16;
        if (more) wfn = *(const s8v*)(Wp + (nt + 4) * 512 + lane * 8);
        const int n0 = nt * 16 + l4 * 4;
        #pragma unroll
        for (int m = 0; m < 3; ++m) {
            f4v acc = {0.f, 0.f, 0.f, 0.f};
            acc = __builtin_amdgcn_mfma_f32_16x16x32_bf16(wf, xf[m], acc, 0, 0, 0);
            epi_store<7, OP>(acc, acc, m * 16 + l15, n0, Out, bias1);
        }
        if (more) wf = wfn;
    }
}

// ---- tw2 IN-PLACE: acc all 4 n-tiles in regs; BARRIER between block-wide
//      reads of H and the overwriting stores (race-free). KSH=2, KH=4. ----
template<int AP>
__device__ __forceinline__ void mfma_tw2_inplace(
    const short* __restrict__ Wp, const float* __restrict__ bias,
    short* H, int lane, int wid, PreW<2> pre)
{
    const int l15 = lane & 15, l4 = lane >> 4;
    f4v acc[4][3];
    #pragma unroll
    for (int i = 0; i < 4; ++i)
        #pragma unroll
        for (int m = 0; m < 3; ++m) acc[i][m] = (f4v){0.f, 0.f, 0.f, 0.f};

    s8v wf[2];
    wf[0] = pre.w[0]; wf[1] = pre.w[1];

    #pragma unroll
    for (int kh = 0; kh < 4; ++kh) {
        s8v xf[3][2];
        #pragma unroll
        for (int m = 0; m < 3; ++m)
            #pragma unroll
            for (int ks = 0; ks < 2; ++ks)
                xf[m][ks] = *(const s8v*)(H + (m * 16 + l15) * AP + (kh * 2 + ks) * 32 + l4 * 8);
        #pragma unroll
        for (int i = 0; i < 4; ++i) {
            s8v wfn[2];
            const bool more = (i < 3) || (kh < 3);
            if (more) {
                const int ni  = (i < 3) ? i + 1 : 0;
                const int nkh = (i < 3) ? kh : kh + 1;
                const int nnt = wid + ni * 4;
                #pragma unroll
                for (int ks = 0; ks < 2; ++ks)
                    wfn[ks] = *(const s8v*)(Wp + nnt * (8 * 512) + (nkh * 2 + ks) * 512 + lane * 8);
            }
            #pragma unroll
            for (int m = 0; m < 3; ++m) {
                acc[i][m] = __builtin_amdgcn_mfma_f32_16x16x32_bf16(wf[0], xf[m][0], acc[i][m], 0, 0, 0);
                acc[i][m] = __builtin_amdgcn_mfma_f32_16x16x32_bf16(wf[1], xf[m][1], acc[i][m], 0, 0, 0);
            }
            if (more) { wf[0] = wfn[0]; wf[1] = wfn[1]; }
        }
    }

    BARRIER();   // every wave's H reads complete before any overwrite

    #pragma unroll
    for (int i = 0; i < 4; ++i) {
        const int nt = wid + i * 4;
        const int n0 = nt * 16 + l4 * 4;
        f4v bv = *(const f4v*)(bias + n0);
        #pragma unroll
        for (int m = 0; m < 3; ++m)
            epi_store<0, AP>(acc[i][m], bv, m * 16 + l15, n0, H, nullptr);
    }
}

// ---- K-split persistent-acc layer (tw3), wf rotate-prefetch ----
template<int MT, int KSH, int KH, int NTW, int EPI, int AP, int OP>
__device__ __forceinline__ void mfma_acc(
    const short* __restrict__ Wp, const float* __restrict__ bias,
    const short* A, void* Out,
    const void* aux, int lane, int wid, int ntBase, PreW<KSH> pre)
{
    const int l15 = lane & 15, l4 = lane >> 4;
    const int KS = KSH * KH;
    f4v acc[NTW][MT];
    #pragma unroll
    for (int i = 0; i < NTW; ++i)
        #pragma unroll
        for (int m = 0; m < MT; ++m) acc[i][m] = (f4v){0.f, 0.f, 0.f, 0.f};

    s8v wf[KSH];
    #pragma unroll
    for (int ks = 0; ks < KSH; ++ks) wf[ks] = pre.w[ks];

    #pragma unroll
    for (int kh = 0; kh < KH; ++kh) {
        s8v xf[MT][KSH];
        #pragma unroll
        for (int m = 0; m < MT; ++m)
            #pragma unroll
            for (int ks = 0; ks < KSH; ++ks)
                xf[m][ks] = *(const s8v*)(A + (m * 16 + l15) * AP + (kh * KSH + ks) * 32 + l4 * 8);
        #pragma unroll
        for (int i = 0; i < NTW; ++i) {
            s8v wfn[KSH];
            const bool more = (i + 1 < NTW) || (kh + 1 < KH);
            if (more) {
                const int ni  = (i + 1 < NTW) ? i + 1 : 0;
                const int nkh = (i + 1 < NTW) ? kh : kh + 1;
                const int nnt = wid + (ntBase + ni) * 4;
                #pragma unroll
                for (int ks = 0; ks < KSH; ++ks)
                    wfn[ks] = *(const s8v*)(Wp + nnt * (KS * 512) + (nkh * KSH + ks) * 512 + lane * 8);
            }
            #pragma unroll
            for (int m = 0; m < MT; ++m)
                #pragma unroll
                for (int ks = 0; ks < KSH; ++ks)
                    acc[i][m] = __builtin_amdgcn_mfma_f32_16x16x32_bf16(wf[ks], xf[m][ks], acc[i][m], 0, 0, 0);
            if (more) {
                #pragma unroll
                for (int ks = 0; ks < KSH; ++ks) wf[ks] = wfn[ks];
            }
        }
    }
    #pragma unroll
    for (int i = 0; i < NTW; ++i) {
        const int nt = wid + (ntBase + i) * 4;
        const int n0 = nt * 16 + l4 * 4;
        f4v bv = *(const f4v*)(bias + n0);
        #pragma unroll
        for (int m = 0; m < MT; ++m)
            epi_store<EPI, OP>(acc[i][m], bv, m * 16 + l15, n0, Out, aux);
    }
}

// ---- LayerNorm from bf16 CH: 4 threads/token, 192 active ----
__device__ __forceinline__ void ln_phase(const short* CHb, short* dst, const int dp,
                                         const float* __restrict__ g,
                                         const float* __restrict__ b, int tid)
{
    if (tid < 192) {
        int t = tid >> 2, p = tid & 3;
        const short* cp = CHb + t * 68 + p * 16;
        float c[16];
        #pragma unroll
        for (int i = 0; i < 4; ++i) {
            i2v w = *(const i2v*)(cp + i * 4);
            c[i * 4 + 0] = bf_lo(w[0]); c[i * 4 + 1] = bf_hi(w[0]);
            c[i * 4 + 2] = bf_lo(w[1]); c[i * 4 + 3] = bf_hi(w[1]);
        }
        float s = 0.f, ss = 0.f;
        #pragma unroll
        for (int i = 0; i < 16; ++i) { s += c[i]; ss += c[i] * c[i]; }
        s += __shfl_xor(s, 1); ss += __shfl_xor(ss, 1);
        s += __shfl_xor(s, 2); ss += __shfl_xor(ss, 2);
        float mu = s * (1.0f / 64.0f);
        float var = ss * (1.0f / 64.0f) - mu * mu;
        float rstd = rsqrtf(var + 1e-5f);
        int pk[8];
        #pragma unroll
        for (int i = 0; i < 4; ++i) {
            f4v gv = *(const f4v*)(g + p * 16 + i * 4);
            f4v bvv = *(const f4v*)(b + p * 16 + i * 4);
            float o0 = (c[i * 4 + 0] - mu) * rstd * gv[0] + bvv[0];
            float o1 = (c[i * 4 + 1] - mu) * rstd * gv[1] + bvv[1];
            float o2 = (c[i * 4 + 2] - mu) * rstd * gv[2] + bvv[2];
            float o3 = (c[i * 4 + 3] - mu) * rstd * gv[3] + bvv[3];
            pk[i * 2]     = cvt_pk_bf16(o0, o1);
            pk[i * 2 + 1] = cvt_pk_bf16(o2, o3);
        }
        i4v w0 = {pk[0], pk[1], pk[2], pk[3]};
        i4v w1 = {pk[4], pk[5], pk[6], pk[7]};
        *(i4v*)(dst + t * dp + p * 16) = w0;
        *(i4v*)(dst + t * dp + p * 16 + 8) = w1;
    }
}

// ---- LDS: single arena, 32640 B -> 5 blocks/CU ----
// H    @ 0      [48][264] bf16 = 25344  (T1F out, tw2 in-place, tw3 in)
// tmp7 @ 0      [48][72]  bf16 = 6912   (aln/ao/fb, over dead H head)
// qkv  @ 6912   [48][200] bf16 = 19200  (over dead H mid)
// CHb  @ 26112  [48][68]  bf16 = 6528   (disjoint from H? NO - over H tail,
//                                        written by tw3 epilogue AFTER all H
//                                        reads are in regs; barrier-protected)
// g1   @ 6912   [48][136] bf16 = 13056  (over dead qkv)
// flat @ 0      [16][200] bf16 = 6400   (over dead tmp7/fb)
// hh1  @ 6912   [16][168] bf16 = 5376   (over dead g1)
// part @ 0      [16][16]  f32  = 1024   (over dead flat)
#define LDS_BYTES 32640

__global__ __launch_bounds__(256, 5)
void towers_mfma(const float* __restrict__ x,
                 const float* __restrict__ pos_c,
                 const float* __restrict__ tb2, const float* __restrict__ tb3,
                 const float* __restrict__ ln1g, const float* __restrict__ ln1b,
                 const float* __restrict__ inpb, const float* __restrict__ outb,
                 const float* __restrict__ ln2g, const float* __restrict__ ln2b,
                 const float* __restrict__ ffb1, const float* __restrict__ ffb2,
                 const float* __restrict__ hb1, const float* __restrict__ hb2,
                 const float* __restrict__ hw3, const float* __restrict__ hb3,
                 const short* __restrict__ wsBp,
                 float* __restrict__ out)
{
    __shared__ __align__(16) char smem[LDS_BYTES];

    const int tid = threadIdx.x;
    const int lane = tid & 63, wid = tid >> 6;
    const long long row0 = (long long)blockIdx.x * 16;
    const float* bias1 = (const float*)(wsBp + BIAS1_ELEM);

    short* H    = (short*)smem;              // [48][264]
    short* CHb  = (short*)(smem + 26112);    // [48][68] bf16
    short* tmp7 = (short*)smem;              // aln/ao/fb [48][72] @0
    short* qkv  = (short*)(smem + 6912);     // [48][200]

    // ---- fused tower layer 1: x(global) -> H, EPI7 ----
    PreW<1> preT1f = preloadW<1>(wsBp + OFF_T1F, lane, wid, 1);
    mfma_x1<264>(wsBp + OFF_T1F, x, row0, H, bias1, lane, wid, preT1f);
    PreW<2> preT2 = preloadW<2>(wsBp + OFF_TW2, lane, wid, 8);
    BARRIER();

    // ---- tw2: H -> H in-place (internal barrier) ----
    mfma_tw2_inplace<264>(wsBp + OFF_TW2, tb2, H, lane, wid, preT2);
    PreW<4> preT3 = preloadW<4>(wsBp + OFF_TW3, lane, wid, 8);
    BARRIER();

    // ---- tw3: H -> CHb bf16 (all H reads into regs before epilogue;
    //      CHb overlays H tail 26112..32640 < H end? H ends at 25344 -> CHb
    //      @26112 is actually PAST H end: fully disjoint, no hazard) ----
    mfma_acc<3, 4, 2, 1, 3, 264, 68>(wsBp + OFF_TW3, tb3, H, CHb, pos_c, lane, wid, 0, preT3);
    PreW<2> preINP = preloadW<2>(wsBp + OFF_INP, lane, wid, 2);
    BARRIER();

    // ---- ln1: CHb -> aln(tmp7 @0, over dead H) ----
    ln_phase(CHb, tmp7, 72, ln1g, ln1b, tid);
    BARRIER();

    // ---- qkv: aln(tmp7) -> qkv @6912 (over dead H) ----
    mfma_T<3, 2, 1, 72, 200>(wsBp + OFF_INP, inpb, tmp7, qkv, 192, nullptr, lane, wid, preINP);
    PreW<2> preOUT = preloadW<2>(wsBp + OFF_OUT, lane, wid, 2);
    BARRIER();

    // ---- attention: qkv -> ao(tmp7) ----
    if (tid < 192) {
        int r = tid & 15, hc = tid >> 4;
        int h = hc & 3, cq = hc >> 2;
        const short* qp = qkv + (r * 3 + cq) * 200 + h * 16;
        float qv[16];
        { s8v q0 = *(const s8v*)qp, q1 = *(const s8v*)(qp + 8);
          #pragma unroll
          for (int j = 0; j < 8; ++j) {
              qv[j] = __uint_as_float(((unsigned)(unsigned short)q0[j]) << 16);
              qv[8 + j] = __uint_as_float(((unsigned)(unsigned short)q1[j]) << 16);
          } }
        float sc[3];
        #pragma unroll
        for (int c = 0; c < 3; ++c) {
            const short* kp = qkv + (r * 3 + c) * 200 + 64 + h * 16;
            s8v k0 = *(const s8v*)kp, k1 = *(const s8v*)(kp + 8);
            float acc = 0.f;
            #pragma unroll
            for (int j = 0; j < 8; ++j) {
                acc += qv[j] * __uint_as_float(((unsigned)(unsigned short)k0[j]) << 16)
                     + qv[8 + j] * __uint_as_float(((unsigned)(unsigned short)k1[j]) << 16);
            }
            sc[c] = acc * 0.25f;
        }
        float m = fmaxf(sc[0], fmaxf(sc[1], sc[2]));
        float e0 = __expf(sc[0] - m), e1 = __expf(sc[1] - m), e2 = __expf(sc[2] - m);
        float inv = 1.0f / (e0 + e1 + e2);
        e0 *= inv; e1 *= inv; e2 *= inv;
        float ov[16];
        #pragma unroll
        for (int j = 0; j < 16; ++j) ov[j] = 0.f;
        const float ee[3] = {e0, e1, e2};
        #pragma unroll
        for (int c = 0; c < 3; ++c) {
            const short* vp = qkv + (r * 3 + c) * 200 + 128 + h * 16;
            s8v v0 = *(const s8v*)vp, v1 = *(const s8v*)(vp + 8);
            #pragma unroll
            for (int j = 0; j < 8; ++j) {
                ov[j]     += ee[c] * __uint_as_float(((unsigned)(unsigned short)v0[j]) << 16);
                ov[8 + j] += ee[c] * __uint_as_float(((unsigned)(unsigned short)v1[j]) << 16);
            }
        }
        short* op = tmp7 + (r * 3 + cq) * 72 + h * 16;
        i4v pk;
        pk[0] = cvt_pk_bf16(ov[0], ov[1]);   pk[1] = cvt_pk_bf16(ov[2], ov[3]);
        pk[2] = cvt_pk_bf16(ov[4], ov[5]);   pk[3] = cvt_pk_bf16(ov[6], ov[7]);
        *(i4v*)op = pk;
        pk[0] = cvt_pk_bf16(ov[8], ov[9]);   pk[1] = cvt_pk_bf16(ov[10], ov[11]);
        pk[2] = cvt_pk_bf16(ov[12], ov[13]); pk[3] = cvt_pk_bf16(ov[14], ov[15]);
        *(i4v*)(op + 8) = pk;
    }
    BARRIER();

    // ---- attn out proj: ao(tmp7), CHb += (EPI2 bf16 rmw) ----
    mfma_T<3, 2, 2, 72, 68>(wsBp + OFF_OUT, outb, tmp7, CHb, 64, nullptr, lane, wid, preOUT);
    PreW<2> preFF1 = preloadW<2>(wsBp + OFF_FF1, lane, wid, 2);
    BARRIER();

    // ---- ln2: CHb -> fb(tmp7) ----
    ln_phase(CHb, tmp7, 72, ln2g, ln2b, tid);
    BARRIER();

    // ---- ffn: ff1 fb(tmp7) -> g1 @6912 (over dead qkv); ff2 EPI5 -> flat @0 ----
    short* g1 = (short*)(smem + 6912);       // [48][136]
    mfma_T<3, 2, 0, 72, 136>(wsBp + OFF_FF1, ffb1, tmp7, g1, 128, nullptr, lane, wid, preFF1);
    PreW<4> preFF2 = preloadW<4>(wsBp + OFF_FF2, lane, wid, 4);
    BARRIER();
    short* flat = (short*)smem;              // [16][200] @0 (over dead fb)
    mfma_T<3, 4, 5, 136, 200>(wsBp + OFF_FF2, ffb2, g1, flat, 64, CHb, lane, wid, preFF2);
    PreW<6> preH1 = preloadW<6>(wsBp + OFF_HW1, lane, wid, 6);
    BARRIER();

    // ---- head: hw1 flat -> hh1 @6912 (over dead g1); hw2 EPI6 -> part @0 ----
    short* hh1 = (short*)(smem + 6912);      // [16][168]
    mfma_T<1, 6, 0, 200, 168>(wsBp + OFF_HW1, hb1, flat, hh1, 160, nullptr, lane, wid, preH1);
    PreW<5> preH2 = preloadW<5>(wsBp + OFF_HW2, lane, wid, 5);
    BARRIER();
    float* part = (float*)smem;              // [16][16] @0 (over dead flat)
    mfma_T<1, 5, 6, 168, 16>(wsBp + OFF_HW2, hb2, hh1, part, 64, hw3, lane, wid, preH2);
    BARRIER();

    // ---- final dot reduce ----
    if (tid < 64) {
        int r = tid >> 2, p = tid & 3;
        const float* pp = part + r * 16 + p * 4;
        float acc = pp[0] + pp[1] + pp[2] + pp[3];
        acc += __shfl_xor(acc, 1);
        acc += __shfl_xor(acc, 2);
        if (p == 0) out[row0 + r] = acc + hb3[0];
    }
}

extern "C" void kernel_launch(void* const* d_in, const int* in_sizes, int n_in,
                              void* d_out, int out_size, void* d_ws, size_t ws_size,
                              hipStream_t stream) {
    const float* x     = (const float*)d_in[0];
    const float* w_emb = (const float*)d_in[1];
    const float* pos_d = (const float*)d_in[2];
    const float* pos_c = (const float*)d_in[3];
    const float* tw1   = (const float*)d_in[4];
    const float* tb1   = (const float*)d_in[5];
    const float* tw2   = (const float*)d_in[6];
    const float* tb2   = (const float*)d_in[7];
    const float* tw3   = (const float*)d_in[8];
    const float* tb3   = (const float*)d_in[9];
    const float* ln1g  = (const float*)d_in[10];
    const float* ln1b  = (const float*)d_in[11];
    const float* inpw  = (const float*)d_in[12];
    const float* inpb  = (const float*)d_in[13];
    const float* outw  = (const float*)d_in[14];
    const float* outb  = (const float*)d_in[15];
    const float* ln2g  = (const float*)d_in[16];
    const float* ln2b  = (const float*)d_in[17];
    const float* ffw1  = (const float*)d_in[18];
    const float* ffb1  = (const float*)d_in[19];
    const float* ffw2  = (const float*)d_in[20];
    const float* ffb2  = (const float*)d_in[21];
    const float* hw1   = (const float*)d_in[22];
    const float* hb1   = (const float*)d_in[23];
    const float* hw2   = (const float*)d_in[24];
    const float* hb2   = (const float*)d_in[25];
    const float* hw3   = (const float*)d_in[26];
    const float* hb3   = (const float*)d_in[27];
    float* out = (float*)d_out;
    short* wsBp = (short*)d_ws;              // needs 330752 B

    pack_weights<<<dim3(16, 10), 256, 0, stream>>>(w_emb, tw1, pos_d, tb1,
                                                   tw2, tw3, inpw, outw,
                                                   ffw1, ffw2, hw1, hw2, wsBp);

    const int B = in_sizes[0] / 90;
    towers_mfma<<<B / 16, 256, 0, stream>>>(
        x, pos_c, tb2, tb3,
        ln1g, ln1b, inpb, outb, ln2g, ln2b,
        ffb1, ffb2, hb1, hb2, hw3, hb3, wsBp, out);
}

// Round 21
// 208.979 us; speedup vs baseline: 1.3379x; 1.3379x over previous
//
#include <hip/hip_runtime.h>
#include <math.h>

// Fused TowersMLP, bf16-MFMA, transposed-D, 256-thread / 4-wave.
// R21 = R20 (bf16 CH residual, 32640B LDS) with __launch_bounds__(256,4):
// R20's (256,5) forced VGPR->48 + scratch spills (WRITE 257MB). With (,4)
// the allocator keeps ~64 VGPR (R19 level, no spills) and the HARDWARE
// still fits 5 blocks/CU via the LDS limit (160K/32640=5; 5 waves/SIMD
// needs VGPR<=409, satisfied).
// Frozen invariants: split lgkm barrier (R7 form), bias in epilogue only
// (bias-fold POISON), 8192-block dispatch (persistent grid POISON).

typedef short s8v __attribute__((ext_vector_type(8)));
typedef float f4v __attribute__((ext_vector_type(4)));
typedef int   i2v __attribute__((ext_vector_type(2)));
typedef int   i4v __attribute__((ext_vector_type(4)));

__device__ __forceinline__ short f2bf(float f) {
    unsigned u = __float_as_uint(f);
    unsigned r = (u + 0x7fffu + ((u >> 16) & 1u)) >> 16;   // RNE
    return (short)r;
}
__device__ __forceinline__ int cvt_pk_bf16(float a, float b) {   // lo=a, hi=b
    int r;
    asm("v_cvt_pk_bf16_f32 %0, %1, %2" : "=v"(r) : "v"(a), "v"(b));
    return r;
}
__device__ __forceinline__ float bf_lo(int w) { return __uint_as_float((unsigned)w << 16); }
__device__ __forceinline__ float bf_hi(int w) { return __uint_as_float((unsigned)w & 0xffff0000u); }
__device__ __forceinline__ float silu_f(float v) {
    return v * __builtin_amdgcn_rcpf(1.0f + __expf(-v));   // rcp, arg >= 1
}

// lgkm-only barrier (R7 split form — PROVEN; do not combine into one asm).
#define BARRIER() do {                                        \
    asm volatile("s_waitcnt lgkmcnt(0)" ::: "memory");        \
    __builtin_amdgcn_s_barrier();                             \
    __builtin_amdgcn_sched_barrier(0);                        \
} while (0)

// ---- packed weight offsets (bf16 elems), layout [nt][ks][lane(64)][8] ----
#define OFF_T1F  0        // 256 x 32 fused tw1@BD   NT=16 KS=1
#define OFF_TW2  8192     // 256 x 256  NT=16 KS=8
#define OFF_TW3  73728    // 64 x 256   NT=4  KS=8
#define OFF_INP  90112    // 192 x 64   NT=12 KS=2
#define OFF_OUT  102400   // 64 x 64    NT=4  KS=2
#define OFF_FF1  106496   // 128 x 64   NT=8  KS=2
#define OFF_FF2  114688   // 64 x 128   NT=4  KS=4
#define OFF_HW1  122880   // 160 x 192  NT=10 KS=6
#define OFF_HW2  153600   // 64 x 160   NT=4  KS=5
#define BIAS1_ELEM 163840 // f32[3][256] pos-dependent tower bias (3072 B)
// total ws: 163840*2 + 3072 = 330752 B

__global__ void pack_weights(const float* __restrict__ w_emb, const float* __restrict__ tw1,
                             const float* __restrict__ pos_d, const float* __restrict__ tb1,
                             const float* __restrict__ tw2, const float* __restrict__ tw3,
                             const float* __restrict__ inpw, const float* __restrict__ outw,
                             const float* __restrict__ ffw1, const float* __restrict__ ffw2,
                             const float* __restrict__ hw1, const float* __restrict__ hw2,
                             short* __restrict__ dst)
{
    int L = blockIdx.y;
    if (L == 0) {
        int total = 16 * 512;
        for (int e = blockIdx.x * blockDim.x + threadIdx.x; e < total; e += gridDim.x * blockDim.x) {
            int nt = e >> 9, q = e & 511;
            int l = q >> 3, j = q & 7;
            int n = nt * 16 + (l & 15);
            int k = (l >> 4) * 8 + j;
            float v = 0.f;
            if (k < 30) {
                int gl = k / 10, kk = k - gl * 10;
                const float* trow = tw1 + n * 72 + gl * 24;
                for (int jj = 0; jj < 24; ++jj) v += trow[jj] * w_emb[jj * 10 + kk];
            }
            dst[OFF_T1F + e] = f2bf(v);
        }
        return;
    }
    if (L == 9) {
        float* b1 = (float*)(dst + BIAS1_ELEM);
        for (int e = blockIdx.x * blockDim.x + threadIdx.x; e < 768; e += gridDim.x * blockDim.x) {
            int pos = e >> 8, n = e & 255;
            float v = tb1[n];
            for (int j = 0; j < 72; ++j)
                v += tw1[n * 72 + j] * pos_d[(pos * 3 + j / 24) * 24 + (j % 24)];
            b1[e] = v;
        }
        return;
    }
    const float* W; int K, KS, N, off;
    switch (L) {
      case 1: W = tw2;  K = 256; KS = 8; N = 256; off = OFF_TW2; break;
      case 2: W = tw3;  K = 256; KS = 8; N = 64;  off = OFF_TW3; break;
      case 3: W = inpw; K = 64;  KS = 2; N = 192; off = OFF_INP; break;
      case 4: W = outw; K = 64;  KS = 2; N = 64;  off = OFF_OUT; break;
      case 5: W = ffw1; K = 64;  KS = 2; N = 128; off = OFF_FF1; break;
      case 6: W = ffw2; K = 128; KS = 4; N = 64;  off = OFF_FF2; break;
      case 7: W = hw1;  K = 192; KS = 6; N = 160; off = OFF_HW1; break;
      default:W = hw2;  K = 160; KS = 5; N = 64;  off = OFF_HW2; break;
    }
    int total = (N >> 4) * KS * 512;
    for (int e = blockIdx.x * blockDim.x + threadIdx.x; e < total; e += gridDim.x * blockDim.x) {
        int nt = e / (KS * 512);
        int r  = e - nt * (KS * 512);
        int ks = r >> 9;
        int q  = r & 511;
        int l  = q >> 3, j = q & 7;
        int n  = nt * 16 + (l & 15);
        int k  = ks * 32 + (l >> 4) * 8 + j;
        dst[off + e] = f2bf((k < K) ? W[n * K + k] : 0.0f);
    }
}

// ---- weight preload (first-tile fragments held across barriers) ----
template<int KSH> struct PreW { s8v w[KSH]; };

template<int KSH>
__device__ __forceinline__ PreW<KSH> preloadW(const short* __restrict__ Wp,
                                              int lane, int nt, int ksTotal) {
    PreW<KSH> p;
    #pragma unroll
    for (int ks = 0; ks < KSH; ++ks)
        p.w[ks] = *(const s8v*)(Wp + nt * (ksTotal * 512) + ks * 512 + lane * 8);
    return p;
}

// ---- shared epilogue (bias added HERE — never in MFMA C); OP compile-time ----
// CH is bf16 [48][68]. EPI:
//  0 silu->bf16, 1 linear->bf16,
//  2 CHb rmw: CHb[t][n0..3] += acc+bias (bf16 in/out)
//  3 CHb write: cvt(acc+bias+pos_c)
//  5 residual: CHb + acc + bias -> flat bf16 [16][OP] (aux = CHb)
//  6 silu(acc+bias) dot hw3 -> f32 partial [16][16]
//  7 silu(acc + B1[t%3]) -> bf16 (bv unused)
template<int EPI, int OP>
__device__ __forceinline__ void epi_store(f4v acc, f4v bv, int t, int n0, void* Out,
                                          const void* aux)
{
    if (EPI == 0 || EPI == 1) {
        float v0 = acc[0] + bv[0], v1 = acc[1] + bv[1];
        float v2 = acc[2] + bv[2], v3 = acc[3] + bv[3];
        if (EPI == 0) { v0 = silu_f(v0); v1 = silu_f(v1); v2 = silu_f(v2); v3 = silu_f(v3); }
        i2v pk; pk[0] = cvt_pk_bf16(v0, v1); pk[1] = cvt_pk_bf16(v2, v3);
        *(i2v*)((short*)Out + t * OP + n0) = pk;
    } else if (EPI == 2) {
        i2v* p = (i2v*)((short*)Out + t * 68 + n0);
        i2v c = *p;
        float o0 = bf_lo(c[0]) + acc[0] + bv[0];
        float o1 = bf_hi(c[0]) + acc[1] + bv[1];
        float o2 = bf_lo(c[1]) + acc[2] + bv[2];
        float o3 = bf_hi(c[1]) + acc[3] + bv[3];
        i2v pk; pk[0] = cvt_pk_bf16(o0, o1); pk[1] = cvt_pk_bf16(o2, o3);
        *p = pk;
    } else if (EPI == 3) {
        const float* pc = (const float*)aux + (t % 3) * 64 + n0;
        i2v pk;
        pk[0] = cvt_pk_bf16(acc[0] + bv[0] + pc[0], acc[1] + bv[1] + pc[1]);
        pk[1] = cvt_pk_bf16(acc[2] + bv[2] + pc[2], acc[3] + bv[3] + pc[3]);
        *(i2v*)((short*)Out + t * 68 + n0) = pk;
    } else if (EPI == 5) {
        const short* chb = (const short*)aux;
        i2v c = *(const i2v*)(chb + t * 68 + n0);
        int rr = t / 3, cc = t - rr * 3;
        i2v pk;
        pk[0] = cvt_pk_bf16(bf_lo(c[0]) + acc[0] + bv[0], bf_hi(c[0]) + acc[1] + bv[1]);
        pk[1] = cvt_pk_bf16(bf_lo(c[1]) + acc[2] + bv[2], bf_hi(c[1]) + acc[3] + bv[3]);
        *(i2v*)((short*)Out + rr * OP + cc * 64 + n0) = pk;
    } else if (EPI == 6) {
        const float* w = (const float*)aux + n0;
        float p = silu_f(acc[0] + bv[0]) * w[0] + silu_f(acc[1] + bv[1]) * w[1]
                + silu_f(acc[2] + bv[2]) * w[2] + silu_f(acc[3] + bv[3]) * w[3];
        ((float*)Out)[t * OP + (n0 >> 2)] = p;
    } else {
        const float* bp = (const float*)aux + (t % 3) * 256 + n0;
        float v0 = silu_f(acc[0] + bp[0]), v1 = silu_f(acc[1] + bp[1]);
        float v2 = silu_f(acc[2] + bp[2]), v3 = silu_f(acc[3] + bp[3]);
        i2v pk; pk[0] = cvt_pk_bf16(v0, v1); pk[1] = cvt_pk_bf16(v2, v3);
        *(i2v*)((short*)Out + t * OP + n0) = pk;
    }
}

// ---- generic transposed MFMA dense layer, preloaded first tile ----
template<int MT, int KS, int EPI, int AP, int OP>
__device__ __forceinline__ void mfma_T(
    const short* __restrict__ Wp,
    const float* __restrict__ bias,
    const short* A, void* Out, int N,
    const void* aux, int lane, int wid, PreW<KS> pre)
{
    const int l15 = lane & 15, l4 = lane >> 4;
    s8v xf[MT][KS];
    #pragma unroll
    for (int m = 0; m < MT; ++m)
        #pragma unroll
        for (int ks = 0; ks < KS; ++ks)
            xf[m][ks] = *(const s8v*)(A + (m * 16 + l15) * AP + ks * 32 + l4 * 8);

    s8v wf[KS];
    #pragma unroll
    for (int ks = 0; ks < KS; ++ks) wf[ks] = pre.w[ks];

    const int NT = N >> 4;
    for (int nt = wid; nt < NT; nt += 4) {
        s8v wfn[KS];
        const bool more = (nt + 4) < NT;
        if (more) {
            #pragma unroll
            for (int ks = 0; ks < KS; ++ks)
                wfn[ks] = *(const s8v*)(Wp + (nt + 4) * (KS * 512) + ks * 512 + lane * 8);
        }
        const int n0 = nt * 16 + l4 * 4;
        f4v bv = {0.f, 0.f, 0.f, 0.f};
        if (EPI != 7) bv = *(const f4v*)(bias + n0);
        #pragma unroll
        for (int m = 0; m < MT; ++m) {
            f4v acc = {0.f, 0.f, 0.f, 0.f};
            #pragma unroll
            for (int ks = 0; ks < KS; ++ks)
                acc = __builtin_amdgcn_mfma_f32_16x16x32_bf16(wf[ks], xf[m][ks], acc, 0, 0, 0);
            epi_store<EPI, OP>(acc, bv, m * 16 + l15, n0, Out, aux);
        }
        if (more) {
            #pragma unroll
            for (int ks = 0; ks < KS; ++ks) wf[ks] = wfn[ks];
        }
    }
}

// ---- fused first layer: A-fragments loaded DIRECTLY from global x ----
template<int OP>
__device__ __forceinline__ void mfma_x1(
    const short* __restrict__ Wp, const float* __restrict__ x, long long row0,
    void* Out, const float* __restrict__ bias1,
    int lane, int wid, PreW<1> pre)
{
    const int l15 = lane & 15, l4 = lane >> 4;
    s8v xf[3];
    #pragma unroll
    for (int m = 0; m < 3; ++m) {
        int t = m * 16 + l15;
        int r = t / 3, c = t - r * 3;
        const float* xp = x + (row0 + r) * 90 + c * 30 + l4 * 8;
        float2 a = *(const float2*)xp;
        float2 b = *(const float2*)(xp + 2);
        float2 d = *(const float2*)(xp + 4);
        float2 e = (l4 < 3) ? *(const float2*)(xp + 6) : make_float2(0.f, 0.f);
        i4v pk;
        pk[0] = cvt_pk_bf16(a.x, a.y);
        pk[1] = cvt_pk_bf16(b.x, b.y);
        pk[2] = cvt_pk_bf16(d.x, d.y);
        pk[3] = cvt_pk_bf16(e.x, e.y);
        xf[m] = *(s8v*)&pk;
    }

    s8v wf = pre.w[0];
    for (int nt = wid; nt < 16; nt += 4) {
        s8v wfn;
        const bool more = (nt + 4) < 16;
        if (more) wfn = *(const s8v*)(Wp + (nt + 4) * 512 + lane * 8);
        const int n0 = nt * 16 + l4 * 4;
        #pragma unroll
        for (int m = 0; m < 3; ++m) {
            f4v acc = {0.f, 0.f, 0.f, 0.f};
            acc = __builtin_amdgcn_mfma_f32_16x16x32_bf16(wf, xf[m], acc, 0, 0, 0);
            epi_store<7, OP>(acc, acc, m * 16 + l15, n0, Out, bias1);
        }
        if (more) wf = wfn;
    }
}

// ---- tw2 IN-PLACE: acc all 4 n-tiles in regs; BARRIER between block-wide
//      reads of H and the overwriting stores (race-free). KSH=2, KH=4. ----
template<int AP>
__device__ __forceinline__ void mfma_tw2_inplace(
    const short* __restrict__ Wp, const float* __restrict__ bias,
    short* H, int lane, int wid, PreW<2> pre)
{
    const int l15 = lane & 15, l4 = lane >> 4;
    f4v acc[4][3];
    #pragma unroll
    for (int i = 0; i < 4; ++i)
        #pragma unroll
        for (int m = 0; m < 3; ++m) acc[i][m] = (f4v){0.f, 0.f, 0.f, 0.f};

    s8v wf[2];
    wf[0] = pre.w[0]; wf[1] = pre.w[1];

    #pragma unroll
    for (int kh = 0; kh < 4; ++kh) {
        s8v xf[3][2];
        #pragma unroll
        for (int m = 0; m < 3; ++m)
            #pragma unroll
            for (int ks = 0; ks < 2; ++ks)
                xf[m][ks] = *(const s8v*)(H + (m * 16 + l15) * AP + (kh * 2 + ks) * 32 + l4 * 8);
        #pragma unroll
        for (int i = 0; i < 4; ++i) {
            s8v wfn[2];
            const bool more = (i < 3) || (kh < 3);
            if (more) {
                const int ni  = (i < 3) ? i + 1 : 0;
                const int nkh = (i < 3) ? kh : kh + 1;
                const int nnt = wid + ni * 4;
                #pragma unroll
                for (int ks = 0; ks < 2; ++ks)
                    wfn[ks] = *(const s8v*)(Wp + nnt * (8 * 512) + (nkh * 2 + ks) * 512 + lane * 8);
            }
            #pragma unroll
            for (int m = 0; m < 3; ++m) {
                acc[i][m] = __builtin_amdgcn_mfma_f32_16x16x32_bf16(wf[0], xf[m][0], acc[i][m], 0, 0, 0);
                acc[i][m] = __builtin_amdgcn_mfma_f32_16x16x32_bf16(wf[1], xf[m][1], acc[i][m], 0, 0, 0);
            }
            if (more) { wf[0] = wfn[0]; wf[1] = wfn[1]; }
        }
    }

    BARRIER();   // every wave's H reads complete before any overwrite

    #pragma unroll
    for (int i = 0; i < 4; ++i) {
        const int nt = wid + i * 4;
        const int n0 = nt * 16 + l4 * 4;
        f4v bv = *(const f4v*)(bias + n0);
        #pragma unroll
        for (int m = 0; m < 3; ++m)
            epi_store<0, AP>(acc[i][m], bv, m * 16 + l15, n0, H, nullptr);
    }
}

// ---- K-split persistent-acc layer (tw3), wf rotate-prefetch ----
template<int MT, int KSH, int KH, int NTW, int EPI, int AP, int OP>
__device__ __forceinline__ void mfma_acc(
    const short* __restrict__ Wp, const float* __restrict__ bias,
    const short* A, void* Out,
    const void* aux, int lane, int wid, int ntBase, PreW<KSH> pre)
{
    const int l15 = lane & 15, l4 = lane >> 4;
    const int KS = KSH * KH;
    f4v acc[NTW][MT];
    #pragma unroll
    for (int i = 0; i < NTW; ++i)
        #pragma unroll
        for (int m = 0; m < MT; ++m) acc[i][m] = (f4v){0.f, 0.f, 0.f, 0.f};

    s8v wf[KSH];
    #pragma unroll
    for (int ks = 0; ks < KSH; ++ks) wf[ks] = pre.w[ks];

    #pragma unroll
    for (int kh = 0; kh < KH; ++kh) {
        s8v xf[MT][KSH];
        #pragma unroll
        for (int m = 0; m < MT; ++m)
            #pragma unroll
            for (int ks = 0; ks < KSH; ++ks)
                xf[m][ks] = *(const s8v*)(A + (m * 16 + l15) * AP + (kh * KSH + ks) * 32 + l4 * 8);
        #pragma unroll
        for (int i = 0; i < NTW; ++i) {
            s8v wfn[KSH];
            const bool more = (i + 1 < NTW) || (kh + 1 < KH);
            if (more) {
                const int ni  = (i + 1 < NTW) ? i + 1 : 0;
                const int nkh = (i + 1 < NTW) ? kh : kh + 1;
                const int nnt = wid + (ntBase + ni) * 4;
                #pragma unroll
                for (int ks = 0; ks < KSH; ++ks)
                    wfn[ks] = *(const s8v*)(Wp + nnt * (KS * 512) + (nkh * KSH + ks) * 512 + lane * 8);
            }
            #pragma unroll
            for (int m = 0; m < MT; ++m)
                #pragma unroll
                for (int ks = 0; ks < KSH; ++ks)
                    acc[i][m] = __builtin_amdgcn_mfma_f32_16x16x32_bf16(wf[ks], xf[m][ks], acc[i][m], 0, 0, 0);
            if (more) {
                #pragma unroll
                for (int ks = 0; ks < KSH; ++ks) wf[ks] = wfn[ks];
            }
        }
    }
    #pragma unroll
    for (int i = 0; i < NTW; ++i) {
        const int nt = wid + (ntBase + i) * 4;
        const int n0 = nt * 16 + l4 * 4;
        f4v bv = *(const f4v*)(bias + n0);
        #pragma unroll
        for (int m = 0; m < MT; ++m)
            epi_store<EPI, OP>(acc[i][m], bv, m * 16 + l15, n0, Out, aux);
    }
}

// ---- LayerNorm from bf16 CH: 4 threads/token, 192 active ----
__device__ __forceinline__ void ln_phase(const short* CHb, short* dst, const int dp,
                                         const float* __restrict__ g,
                                         const float* __restrict__ b, int tid)
{
    if (tid < 192) {
        int t = tid >> 2, p = tid & 3;
        const short* cp = CHb + t * 68 + p * 16;
        float c[16];
        #pragma unroll
        for (int i = 0; i < 4; ++i) {
            i2v w = *(const i2v*)(cp + i * 4);
            c[i * 4 + 0] = bf_lo(w[0]); c[i * 4 + 1] = bf_hi(w[0]);
            c[i * 4 + 2] = bf_lo(w[1]); c[i * 4 + 3] = bf_hi(w[1]);
        }
        float s = 0.f, ss = 0.f;
        #pragma unroll
        for (int i = 0; i < 16; ++i) { s += c[i]; ss += c[i] * c[i]; }
        s += __shfl_xor(s, 1); ss += __shfl_xor(ss, 1);
        s += __shfl_xor(s, 2); ss += __shfl_xor(ss, 2);
        float mu = s * (1.0f / 64.0f);
        float var = ss * (1.0f / 64.0f) - mu * mu;
        float rstd = rsqrtf(var + 1e-5f);
        int pk[8];
        #pragma unroll
        for (int i = 0; i < 4; ++i) {
            f4v gv = *(const f4v*)(g + p * 16 + i * 4);
            f4v bvv = *(const f4v*)(b + p * 16 + i * 4);
            float o0 = (c[i * 4 + 0] - mu) * rstd * gv[0] + bvv[0];
            float o1 = (c[i * 4 + 1] - mu) * rstd * gv[1] + bvv[1];
            float o2 = (c[i * 4 + 2] - mu) * rstd * gv[2] + bvv[2];
            float o3 = (c[i * 4 + 3] - mu) * rstd * gv[3] + bvv[3];
            pk[i * 2]     = cvt_pk_bf16(o0, o1);
            pk[i * 2 + 1] = cvt_pk_bf16(o2, o3);
        }
        i4v w0 = {pk[0], pk[1], pk[2], pk[3]};
        i4v w1 = {pk[4], pk[5], pk[6], pk[7]};
        *(i4v*)(dst + t * dp + p * 16) = w0;
        *(i4v*)(dst + t * dp + p * 16 + 8) = w1;
    }
}

// ---- LDS: single arena, 32640 B -> 5 blocks/CU (LDS-limited) ----
// H    @ 0      [48][264] bf16 = 25344
// tmp7 @ 0      [48][72]  bf16 = 6912   (over dead H head)
// qkv  @ 6912   [48][200] bf16 = 19200  (over dead H mid)
// CHb  @ 26112  [48][68]  bf16 = 6528   (past H end, disjoint)
// g1   @ 6912   [48][136] bf16 = 13056  (over dead qkv)
// flat @ 0      [16][200] bf16 = 6400   (over dead tmp7/fb)
// hh1  @ 6912   [16][168] bf16 = 5376   (over dead g1)
// part @ 0      [16][16]  f32  = 1024   (over dead flat)
#define LDS_BYTES 32640

__global__ __launch_bounds__(256, 4)
void towers_mfma(const float* __restrict__ x,
                 const float* __restrict__ pos_c,
                 const float* __restrict__ tb2, const float* __restrict__ tb3,
                 const float* __restrict__ ln1g, const float* __restrict__ ln1b,
                 const float* __restrict__ inpb, const float* __restrict__ outb,
                 const float* __restrict__ ln2g, const float* __restrict__ ln2b,
                 const float* __restrict__ ffb1, const float* __restrict__ ffb2,
                 const float* __restrict__ hb1, const float* __restrict__ hb2,
                 const float* __restrict__ hw3, const float* __restrict__ hb3,
                 const short* __restrict__ wsBp,
                 float* __restrict__ out)
{
    __shared__ __align__(16) char smem[LDS_BYTES];

    const int tid = threadIdx.x;
    const int lane = tid & 63, wid = tid >> 6;
    const long long row0 = (long long)blockIdx.x * 16;
    const float* bias1 = (const float*)(wsBp + BIAS1_ELEM);

    short* H    = (short*)smem;              // [48][264]
    short* CHb  = (short*)(smem + 26112);    // [48][68] bf16
    short* tmp7 = (short*)smem;              // aln/ao/fb [48][72] @0
    short* qkv  = (short*)(smem + 6912);     // [48][200]

    // ---- fused tower layer 1: x(global) -> H, EPI7 ----
    PreW<1> preT1f = preloadW<1>(wsBp + OFF_T1F, lane, wid, 1);
    mfma_x1<264>(wsBp + OFF_T1F, x, row0, H, bias1, lane, wid, preT1f);
    PreW<2> preT2 = preloadW<2>(wsBp + OFF_TW2, lane, wid, 8);
    BARRIER();

    // ---- tw2: H -> H in-place (internal barrier) ----
    mfma_tw2_inplace<264>(wsBp + OFF_TW2, tb2, H, lane, wid, preT2);
    PreW<4> preT3 = preloadW<4>(wsBp + OFF_TW3, lane, wid, 8);
    BARRIER();

    // ---- tw3: H -> CHb bf16 (CHb @26112 past H end: disjoint) ----
    mfma_acc<3, 4, 2, 1, 3, 264, 68>(wsBp + OFF_TW3, tb3, H, CHb, pos_c, lane, wid, 0, preT3);
    PreW<2> preINP = preloadW<2>(wsBp + OFF_INP, lane, wid, 2);
    BARRIER();

    // ---- ln1: CHb -> aln(tmp7 @0, over dead H) ----
    ln_phase(CHb, tmp7, 72, ln1g, ln1b, tid);
    BARRIER();

    // ---- qkv: aln(tmp7) -> qkv @6912 (over dead H) ----
    mfma_T<3, 2, 1, 72, 200>(wsBp + OFF_INP, inpb, tmp7, qkv, 192, nullptr, lane, wid, preINP);
    PreW<2> preOUT = preloadW<2>(wsBp + OFF_OUT, lane, wid, 2);
    BARRIER();

    // ---- attention: qkv -> ao(tmp7) ----
    if (tid < 192) {
        int r = tid & 15, hc = tid >> 4;
        int h = hc & 3, cq = hc >> 2;
        const short* qp = qkv + (r * 3 + cq) * 200 + h * 16;
        float qv[16];
        { s8v q0 = *(const s8v*)qp, q1 = *(const s8v*)(qp + 8);
          #pragma unroll
          for (int j = 0; j < 8; ++j) {
              qv[j] = __uint_as_float(((unsigned)(unsigned short)q0[j]) << 16);
              qv[8 + j] = __uint_as_float(((unsigned)(unsigned short)q1[j]) << 16);
          } }
        float sc[3];
        #pragma unroll
        for (int c = 0; c < 3; ++c) {
            const short* kp = qkv + (r * 3 + c) * 200 + 64 + h * 16;
            s8v k0 = *(const s8v*)kp, k1 = *(const s8v*)(kp + 8);
            float acc = 0.f;
            #pragma unroll
            for (int j = 0; j < 8; ++j) {
                acc += qv[j] * __uint_as_float(((unsigned)(unsigned short)k0[j]) << 16)
                     + qv[8 + j] * __uint_as_float(((unsigned)(unsigned short)k1[j]) << 16);
            }
            sc[c] = acc * 0.25f;
        }
        float m = fmaxf(sc[0], fmaxf(sc[1], sc[2]));
        float e0 = __expf(sc[0] - m), e1 = __expf(sc[1] - m), e2 = __expf(sc[2] - m);
        float inv = 1.0f / (e0 + e1 + e2);
        e0 *= inv; e1 *= inv; e2 *= inv;
        float ov[16];
        #pragma unroll
        for (int j = 0; j < 16; ++j) ov[j] = 0.f;
        const float ee[3] = {e0, e1, e2};
        #pragma unroll
        for (int c = 0; c < 3; ++c) {
            const short* vp = qkv + (r * 3 + c) * 200 + 128 + h * 16;
            s8v v0 = *(const s8v*)vp, v1 = *(const s8v*)(vp + 8);
            #pragma unroll
            for (int j = 0; j < 8; ++j) {
                ov[j]     += ee[c] * __uint_as_float(((unsigned)(unsigned short)v0[j]) << 16);
                ov[8 + j] += ee[c] * __uint_as_float(((unsigned)(unsigned short)v1[j]) << 16);
            }
        }
        short* op = tmp7 + (r * 3 + cq) * 72 + h * 16;
        i4v pk;
        pk[0] = cvt_pk_bf16(ov[0], ov[1]);   pk[1] = cvt_pk_bf16(ov[2], ov[3]);
        pk[2] = cvt_pk_bf16(ov[4], ov[5]);   pk[3] = cvt_pk_bf16(ov[6], ov[7]);
        *(i4v*)op = pk;
        pk[0] = cvt_pk_bf16(ov[8], ov[9]);   pk[1] = cvt_pk_bf16(ov[10], ov[11]);
        pk[2] = cvt_pk_bf16(ov[12], ov[13]); pk[3] = cvt_pk_bf16(ov[14], ov[15]);
        *(i4v*)(op + 8) = pk;
    }
    BARRIER();

    // ---- attn out proj: ao(tmp7), CHb += (EPI2 bf16 rmw) ----
    mfma_T<3, 2, 2, 72, 68>(wsBp + OFF_OUT, outb, tmp7, CHb, 64, nullptr, lane, wid, preOUT);
    PreW<2> preFF1 = preloadW<2>(wsBp + OFF_FF1, lane, wid, 2);
    BARRIER();

    // ---- ln2: CHb -> fb(tmp7) ----
    ln_phase(CHb, tmp7, 72, ln2g, ln2b, tid);
    BARRIER();

    // ---- ffn: ff1 fb(tmp7) -> g1 @6912 (over dead qkv); ff2 EPI5 -> flat @0 ----
    short* g1 = (short*)(smem + 6912);       // [48][136]
    mfma_T<3, 2, 0, 72, 136>(wsBp + OFF_FF1, ffb1, tmp7, g1, 128, nullptr, lane, wid, preFF1);
    PreW<4> preFF2 = preloadW<4>(wsBp + OFF_FF2, lane, wid, 4);
    BARRIER();
    short* flat = (short*)smem;              // [16][200] @0 (over dead fb)
    mfma_T<3, 4, 5, 136, 200>(wsBp + OFF_FF2, ffb2, g1, flat, 64, CHb, lane, wid, preFF2);
    PreW<6> preH1 = preloadW<6>(wsBp + OFF_HW1, lane, wid, 6);
    BARRIER();

    // ---- head: hw1 flat -> hh1 @6912 (over dead g1); hw2 EPI6 -> part @0 ----
    short* hh1 = (short*)(smem + 6912);      // [16][168]
    mfma_T<1, 6, 0, 200, 168>(wsBp + OFF_HW1, hb1, flat, hh1, 160, nullptr, lane, wid, preH1);
    PreW<5> preH2 = preloadW<5>(wsBp + OFF_HW2, lane, wid, 5);
    BARRIER();
    float* part = (float*)smem;              // [16][16] @0 (over dead flat)
    mfma_T<1, 5, 6, 168, 16>(wsBp + OFF_HW2, hb2, hh1, part, 64, hw3, lane, wid, preH2);
    BARRIER();

    // ---- final dot reduce ----
    if (tid < 64) {
        int r = tid >> 2, p = tid & 3;
        const float* pp = part + r * 16 + p * 4;
        float acc = pp[0] + pp[1] + pp[2] + pp[3];
        acc += __shfl_xor(acc, 1);
        acc += __shfl_xor(acc, 2);
        if (p == 0) out[row0 + r] = acc + hb3[0];
    }
}

extern "C" void kernel_launch(void* const* d_in, const int* in_sizes, int n_in,
                              void* d_out, int out_size, void* d_ws, size_t ws_size,
                              hipStream_t stream) {
    const float* x     = (const float*)d_in[0];
    const float* w_emb = (const float*)d_in[1];
    const float* pos_d = (const float*)d_in[2];
    const float* pos_c = (const float*)d_in[3];
    const float* tw1   = (const float*)d_in[4];
    const float* tb1   = (const float*)d_in[5];
    const float* tw2   = (const float*)d_in[6];
    const float* tb2   = (const float*)d_in[7];
    const float* tw3   = (const float*)d_in[8];
    const float* tb3   = (const float*)d_in[9];
    const float* ln1g  = (const float*)d_in[10];
    const float* ln1b  = (const float*)d_in[11];
    const float* inpw  = (const float*)d_in[12];
    const float* inpb  = (const float*)d_in[13];
    const float* outw  = (const float*)d_in[14];
    const float* outb  = (const float*)d_in[15];
    const float* ln2g  = (const float*)d_in[16];
    const float* ln2b  = (const float*)d_in[17];
    const float* ffw1  = (const float*)d_in[18];
    const float* ffb1  = (const float*)d_in[19];
    const float* ffw2  = (const float*)d_in[20];
    const float* ffb2  = (const float*)d_in[21];
    const float* hw1   = (const float*)d_in[22];
    const float* hb1   = (const float*)d_in[23];
    const float* hw2   = (const float*)d_in[24];
    const float* hb2   = (const float*)d_in[25];
    const float* hw3   = (const float*)d_in[26];
    const float* hb3   = (const float*)d_in[27];
    float* out = (float*)d_out;
    short* wsBp = (short*)d_ws;              // needs 330752 B

    pack_weights<<<dim3(16, 10), 256, 0, stream>>>(w_emb, tw1, pos_d, tb1,
                                                   tw2, tw3, inpw, outw,
                                                   ffw1, ffw2, hw1, hw2, wsBp);

    const int B = in_sizes[0] / 90;
    towers_mfma<<<B / 16, 256, 0, stream>>>(
        x, pos_c, tb2, tb3,
        ln1g, ln1b, inpb, outb, ln2g, ln2b,
        ffb1, ffb2, hb1, hb2, hw3, hb3, wsBp, out);
}